// Round 11
// baseline (663.302 us; speedup 1.0000x reference)
//
#include <hip/hip_runtime.h>
#include <hip/hip_bf16.h>
#include <math.h>

// Problem constants
#define NN 116           // nodes
#define NE 1160          // edges
#define CCH 256          // channels after conv
#define FF 653           // feature dim
#define KP 672           // padded feature stride (bf16), mult of 32
#define MM (NN*CCH)      // 29696 GEMM rows (= 232 * 128)
#define NPAD 768         // padded N for weight matrix (6 * 128)
#define NT6 (NPAD/128)   // 6 N-tiles
#define NKS (2*KP/32)    // 42 K-steps across the two concatenated passes
#define SZH ((size_t)MM*KP)   // elems per bf16 h buffer

typedef unsigned short ushort;
typedef short bf16x8 __attribute__((ext_vector_type(8)));
typedef float f32x4 __attribute__((ext_vector_type(4)));

// ---- bf16 helpers (bit-level) ----------------------------------------------
__device__ __forceinline__ float bfbits_to_f(ushort u) {
    unsigned int w = ((unsigned int)u) << 16;
    return __uint_as_float(w);
}
__device__ __forceinline__ ushort f_to_bfbits(float f) {   // RTNE
    unsigned int u = __float_as_uint(f);
    u += 0x7FFFu + ((u >> 16) & 1u);
    return (ushort)(u >> 16);
}

__device__ __forceinline__ void gl_lds16(const void* g, void* l) {
    __builtin_amdgcn_global_load_lds(
        (const __attribute__((address_space(1))) unsigned int*)g,
        (__attribute__((address_space(3))) unsigned int*)l, 16, 0, 0);
}

// ---------------------------------------------------------------------------
// CSR build: per-dst incoming-edge source lists.
__global__ void build_csr_k(const int* __restrict__ ei, int* __restrict__ off,
                            int* __restrict__ lst) {
    __shared__ int s_cnt[NN];
    __shared__ int s_off[NN + 1];
    int t = threadIdx.x;
    for (int i = t; i < NN; i += blockDim.x) s_cnt[i] = 0;
    __syncthreads();
    for (int e = t; e < NE; e += blockDim.x) atomicAdd(&s_cnt[ei[NE + e]], 1);
    __syncthreads();
    if (t == 0) {
        s_off[0] = 0;
        for (int i = 0; i < NN; ++i) s_off[i + 1] = s_off[i] + s_cnt[i];
    }
    __syncthreads();
    for (int i = t; i < NN; i += blockDim.x) { off[i] = s_off[i]; s_cnt[i] = 0; }
    if (t == 0) off[NN] = s_off[NN];
    __syncthreads();
    for (int e = t; e < NE; e += blockDim.x) {
        int d = ei[NE + e];
        int p = atomicAdd(&s_cnt[d], 1);
        lst[s_off[d] + p] = ei[e];
    }
}

// ---------------------------------------------------------------------------
// Quantize + concat weights: Wc[2][NPAD][KP] bf16; pass0=Wl, pass1=Wr, zero pad.
__global__ void build_wc_k(const float* __restrict__ wl, const float* __restrict__ wr,
                           ushort* __restrict__ wc) {
    int idx = blockIdx.x * 256 + threadIdx.x;
    const int total = 2 * NPAD * KP;
    if (idx >= total) return;
    int k = idx % KP;
    int rem = idx / KP;
    int n = rem % NPAD;
    int p = rem / NPAD;
    float v = 0.f;
    if (n < FF && k < FF) v = (p ? wr : wl)[(size_t)n * FF + k];
    wc[idx] = f_to_bfbits(v);
}

// ---------------------------------------------------------------------------
// Grouped Conv1d -> bf16 h [MM][KP], zero pads.
// Block = (node n, group g); x window (16 in-ch x 657 = 42KB) staged in LDS
// once (read from HBM exactly once). Wave w handles out-channel chunk w*16:
// the selector goes through readfirstlane -> provably SGPR -> all weight and
// bias loads ride the scalar pipe (R4's bug was tid-derived selector WITHOUT
// readfirstlane: divergent => 2.6GB of per-lane weight fetches).
// Per f-position: 80 ds_read (x, reused 16x) + 1280 FMA (16 indep chains).
__global__ __launch_bounds__(256) void conv1d_k(
    const float* __restrict__ x, const float* __restrict__ w,
    const float* __restrict__ b, ushort* __restrict__ h) {
    __shared__ float sx[16 * 657 + 32];   // +32 pad: f<=703 window reads stay in-bounds
    const int n   = blockIdx.x;
    const int g   = blockIdx.y;
    const int tid = threadIdx.x;
    const float* xg = x + ((size_t)n * 64 + g * 16) * 657;
    for (int i = tid; i < 16 * 657; i += 256) sx[i] = xg[i];
    if (tid < 32) sx[16 * 657 + tid] = 0.f;
    __syncthreads();
    const int wv   = __builtin_amdgcn_readfirstlane(tid >> 6);  // wave id, SGPR
    const int lane = tid & 63;
    const int o0   = g * 64 + wv * 16;            // scalar
    const float* wq = w + o0 * 80;                // scalar base -> s_load path
    float bv[16];
#pragma unroll
    for (int oo = 0; oo < 16; ++oo) bv[oo] = b[o0 + oo];

#pragma unroll 1
    for (int fc = 0; fc < 11; ++fc) {
        const int f = fc * 64 + lane;             // 0..703
        float xv[80];
#pragma unroll
        for (int i = 0; i < 16; ++i)
#pragma unroll
            for (int k = 0; k < 5; ++k)
                xv[i * 5 + k] = sx[i * 657 + f + k];
        float acc[16];
#pragma unroll
        for (int oo = 0; oo < 16; ++oo) acc[oo] = bv[oo];
#pragma unroll
        for (int i = 0; i < 16; ++i)
#pragma unroll
            for (int oo = 0; oo < 16; ++oo) {
                const float* wp = wq + oo * 80 + i * 5;   // scalar + imm offs
                acc[oo] = fmaf(xv[i * 5 + 0], wp[0], acc[oo]);
                acc[oo] = fmaf(xv[i * 5 + 1], wp[1], acc[oo]);
                acc[oo] = fmaf(xv[i * 5 + 2], wp[2], acc[oo]);
                acc[oo] = fmaf(xv[i * 5 + 3], wp[3], acc[oo]);
                acc[oo] = fmaf(xv[i * 5 + 4], wp[4], acc[oo]);
            }
        if (f < FF) {
#pragma unroll
            for (int oo = 0; oo < 16; ++oo)
                h[(size_t)(n * CCH + o0 + oo) * KP + f] = f_to_bfbits(acc[oo]);
        } else if (f < KP) {
#pragma unroll
            for (int oo = 0; oo < 16; ++oo)
                h[(size_t)(n * CCH + o0 + oo) * KP + f] = 0;
        }
    }
}

// ---------------------------------------------------------------------------
// Transposed segment-max (layers 1,2). Block = (channel c, 32-feature chunk).
// All 116 node rows for this (c,chunk) staged in LDS once; edge-max reads LDS.
__global__ __launch_bounds__(256) void seg_maxT_k(
    const ushort* __restrict__ h, ushort* __restrict__ agg,
    const int* __restrict__ off, const int* __restrict__ lst) {
    __shared__ uint4 sh[NN * 4];            // [n][sub] : 32 bf16 per node
    const int c  = blockIdx.x;              // 0..255
    const int f0 = blockIdx.y * 32;         // 0..640
    const int t  = threadIdx.x;
    for (int u = t; u < NN * 4; u += 256) {
        int n = u >> 2, sub = u & 3;
        sh[u] = *(const uint4*)(h + ((size_t)(n * CCH + c)) * KP + f0 + sub * 8);
    }
    __syncthreads();
    for (int u = t; u < NN * 4; u += 256) {
        int n = u >> 2, sub = u & 3;
        int o0 = off[n], o1 = off[n + 1];
        uint4 outv;
        if (o0 == o1) {
            outv = make_uint4(0, 0, 0, 0);
        } else {
            float m[8];
#pragma unroll
            for (int i = 0; i < 8; ++i) m[i] = -3.4e38f;
            for (int e = o0; e < o1; ++e) {
                int s = lst[e];
                uint4 v = sh[s * 4 + sub];
                unsigned int uu[4] = {v.x, v.y, v.z, v.w};
#pragma unroll
                for (int q = 0; q < 4; ++q) {
                    float lo = __uint_as_float(uu[q] << 16);
                    float hi = __uint_as_float(uu[q] & 0xFFFF0000u);
                    m[2*q]   = fmaxf(m[2*q],   lo);
                    m[2*q+1] = fmaxf(m[2*q+1], hi);
                }
            }
            unsigned int o[4];
#pragma unroll
            for (int q = 0; q < 4; ++q) {
                unsigned int a  = __float_as_uint(m[2*q])   >> 16;
                unsigned int bq = __float_as_uint(m[2*q+1]) & 0xFFFF0000u;
                o[q] = a | bq;
            }
            outv = make_uint4(o[0], o[1], o[2], o[3]);
        }
        *(uint4*)(agg + ((size_t)(n * CCH + c)) * KP + f0 + sub * 8) = outv;
    }
}

// ---------------------------------------------------------------------------
// Layer-3 fused: aggP[c][f] = mean_n seg_max(h)[n,c,f], h2P[c][f] = mean_n h.
__global__ __launch_bounds__(256) void seg_pool2_k(
    const ushort* __restrict__ h, ushort* __restrict__ aggP,
    ushort* __restrict__ h2P,
    const int* __restrict__ off, const int* __restrict__ lst) {
    __shared__ uint4 sh[NN * 4];
    __shared__ float pm[NN][32];            // per-node maxes fp32
    const int c  = blockIdx.x;
    const int f0 = blockIdx.y * 32;
    const int t  = threadIdx.x;
    for (int u = t; u < NN * 4; u += 256) {
        int n = u >> 2, sub = u & 3;
        sh[u] = *(const uint4*)(h + ((size_t)(n * CCH + c)) * KP + f0 + sub * 8);
    }
    __syncthreads();
    for (int u = t; u < NN * 4; u += 256) {
        int n = u >> 2, sub = u & 3;
        int o0 = off[n], o1 = off[n + 1];
        float m[8];
        if (o0 == o1) {
#pragma unroll
            for (int i = 0; i < 8; ++i) m[i] = 0.f;
        } else {
#pragma unroll
            for (int i = 0; i < 8; ++i) m[i] = -3.4e38f;
            for (int e = o0; e < o1; ++e) {
                int s = lst[e];
                uint4 v = sh[s * 4 + sub];
                unsigned int uu[4] = {v.x, v.y, v.z, v.w};
#pragma unroll
                for (int q = 0; q < 4; ++q) {
                    float lo = __uint_as_float(uu[q] << 16);
                    float hi = __uint_as_float(uu[q] & 0xFFFF0000u);
                    m[2*q]   = fmaxf(m[2*q],   lo);
                    m[2*q+1] = fmaxf(m[2*q+1], hi);
                }
            }
#pragma unroll
            for (int i = 0; i < 8; ++i)
                m[i] = __uint_as_float(__float_as_uint(m[i]) & 0xFFFF0000u);
        }
#pragma unroll
        for (int i = 0; i < 8; ++i) pm[n][sub * 8 + i] = m[i];
    }
    __syncthreads();
    if (t < 32) {
        const float inv = 1.0f / NN;
        float sa = 0.f, s2 = 0.f;
        for (int n = 0; n < NN; ++n) {
            sa += pm[n][t];
            uint4 v = sh[n * 4 + (t >> 3)];
            unsigned int w = ((const unsigned int*)&v)[(t >> 1) & 3];
            float hv = (t & 1) ? __uint_as_float(w & 0xFFFF0000u)
                               : __uint_as_float(w << 16);
            s2 += hv;
        }
        aggP[(size_t)c * KP + f0 + t] = f_to_bfbits(sa * inv);
        h2P [(size_t)c * KP + f0 + t] = f_to_bfbits(s2 * inv);
    }
}

// ---------------------------------------------------------------------------
// MFMA GEMM, 2-phase prefetch (R9-verified, the 128²-structure ceiling):
// double-buffered LDS, stage K-step t+1 before computing t, one barrier per
// K-step. R10's deeper counted-vmcnt pipeline measured NEUTRAL -> reverted.
// 1D grid, bijective XCD chunking; both-sides LDS swizzle (rule 21).
__global__ __launch_bounds__(256) void sage_gemm_k(
    const ushort* __restrict__ Agg, const ushort* __restrict__ Hcur,
    const ushort* __restrict__ Wc, const float* __restrict__ bias,
    ushort* __restrict__ Hnxt)
{
    __shared__ ushort As[2][128 * 32];
    __shared__ ushort Bs[2][128 * 32];
    const int bid = blockIdx.x;
    const int nwg = gridDim.x;
    const int q   = nwg >> 3, r = nwg & 7;
    const int xcd = bid & 7,  jj = bid >> 3;
    const int wgid = (xcd < r ? xcd * (q + 1) : r * (q + 1) + (xcd - r) * q) + jj;
    const int mt = wgid / NT6;
    const int nt = wgid - mt * NT6;
    const int bm = mt * 128;
    const int bn = nt * 128;
    const int tid  = threadIdx.x;
    const int lane = tid & 63;
    const int wid  = tid >> 6;
    const int wm = (wid >> 1) * 64;
    const int wn = (wid & 1) * 64;

    f32x4 acc[4][4];
#pragma unroll
    for (int i = 0; i < 4; ++i)
#pragma unroll
        for (int j = 0; j < 4; ++j) acc[i][j] = 0.f;

    const int srow   = lane >> 2;                    // 0..15
    const int schunk = lane & 3;                     // 0..3
    const int schk   = (schunk ^ ((srow >> 1) & 3)) * 8;  // swizzled global chunk
    const int lr  = lane & 15;
    const int cc  = lane >> 4;                       // 0..3
    const int kc  = (cc ^ ((lr >> 1) & 3)) * 8;      // swizzled read slot
    const int ldsoff = wid * 16 * 32;                // wave's staging band

#define STAGE(b, kk) do {                                                     \
        int _kk = (kk);                                                       \
        const ushort* _Ab = (_kk < 21) ? Agg : Hcur;                          \
        const ushort* _Wb = Wc + (size_t)(_kk < 21 ? 0 : 1) * NPAD * KP;      \
        int _k0 = (_kk < 21 ? _kk : _kk - 21) * 32;                           \
        const ushort* _ga = _Ab + (size_t)(bm + wid * 16 + srow) * KP + _k0 + schk; \
        const ushort* _gb = _Wb + (size_t)(bn + wid * 16 + srow) * KP + _k0 + schk; \
        gl_lds16(_ga, &As[b][ldsoff]);                                        \
        gl_lds16(_ga + (size_t)64 * KP, &As[b][ldsoff + 64 * 32]);            \
        gl_lds16(_gb, &Bs[b][ldsoff]);                                        \
        gl_lds16(_gb + (size_t)64 * KP, &Bs[b][ldsoff + 64 * 32]);            \
    } while (0)

#define COMPUTE(b) do {                                                       \
        bf16x8 _af[4], _bf[4];                                                \
        _Pragma("unroll")                                                     \
        for (int i = 0; i < 4; ++i)                                           \
            _af[i] = *(const bf16x8*)&As[b][(wm + i * 16 + lr) * 32 + kc];    \
        _Pragma("unroll")                                                     \
        for (int j = 0; j < 4; ++j)                                           \
            _bf[j] = *(const bf16x8*)&Bs[b][(wn + j * 16 + lr) * 32 + kc];    \
        _Pragma("unroll")                                                     \
        for (int i = 0; i < 4; ++i)                                           \
            _Pragma("unroll")                                                 \
            for (int j = 0; j < 4; ++j)                                       \
                acc[i][j] = __builtin_amdgcn_mfma_f32_16x16x32_bf16(          \
                    _af[i], _bf[j], acc[i][j], 0, 0, 0);                      \
    } while (0)

    STAGE(0, 0);
    __syncthreads();                    // buf0 ready (compiler drains vmcnt)
#pragma unroll 1
    for (int kk = 0; kk < NKS; kk += 2) {
        STAGE(1, kk + 1);               // prefetch next while computing cur
        COMPUTE(0);
        __syncthreads();                // buf1 ready; all done reading buf0
        if (kk + 2 < NKS) STAGE(0, kk + 2);
        COMPUTE(1);
        __syncthreads();                // buf0 ready; all done reading buf1
    }
#undef STAGE
#undef COMPUTE

    const int lg = lane >> 4;
#pragma unroll
    for (int j = 0; j < 4; ++j) {
        int n = bn + wn + j * 16 + lr;
        if (n >= KP) continue;
        bool valid = n < FF;
        float bv = valid ? bias[n] : 0.f;
#pragma unroll
        for (int i = 0; i < 4; ++i) {
#pragma unroll
            for (int rgi = 0; rgi < 4; ++rgi) {
                int m = bm + wm + i * 16 + lg * 4 + rgi;
                float v = valid ? (acc[i][j][rgi] + bv) : 0.f;
                Hnxt[(size_t)m * KP + n] = f_to_bfbits(v);
            }
        }
    }
}

// ---------------------------------------------------------------------------
__device__ __forceinline__ float gelu_exact(float v) {
    return 0.5f * v * (1.0f + erff(v * 0.70710678118654752f));
}

__global__ void head_k(const ushort* __restrict__ pool,
                       const float* __restrict__ w1, const float* __restrict__ b1,
                       const float* __restrict__ w2, const float* __restrict__ b2,
                       const float* __restrict__ w3, const float* __restrict__ b3,
                       float* __restrict__ out) {
    __shared__ float row[FF];
    __shared__ float h1[128];
    __shared__ float h2[32];
    __shared__ float sc[4];
    const int c = blockIdx.x;
    const int t = threadIdx.x;
    for (int i = t; i < FF; i += 128) row[i] = bfbits_to_f(pool[(size_t)c * KP + i]);
    __syncthreads();
    {
        const float* wp = w1 + (size_t)t * FF;
        float s = b1[t];
        for (int i = 0; i < FF; ++i) s = fmaf(row[i], wp[i], s);
        h1[t] = gelu_exact(s);
    }
    __syncthreads();
    if (t < 32) {
        const float* wp = w2 + (size_t)t * 128;
        float s = b2[t];
#pragma unroll
        for (int i = 0; i < 128; ++i) s = fmaf(h1[i], wp[i], s);
        h2[t] = gelu_exact(s);
    }
    __syncthreads();
    if (t < 4) {
        const float* wp = w3 + (size_t)t * 32;
        float s = b3[t];
#pragma unroll
        for (int i = 0; i < 32; ++i) s = fmaf(h2[i], wp[i], s);
        sc[t] = s;
    }
    __syncthreads();
    if (t < 4) {
        float mx = fmaxf(fmaxf(sc[0], sc[1]), fmaxf(sc[2], sc[3]));
        float e0 = __expf(sc[0] - mx), e1 = __expf(sc[1] - mx);
        float e2 = __expf(sc[2] - mx), e3 = __expf(sc[3] - mx);
        float inv = 1.0f / (e0 + e1 + e2 + e3);
        float ev = (t == 0) ? e0 : (t == 1) ? e1 : (t == 2) ? e2 : e3;
        out[(size_t)c * 4 + t] = ev * inv;
    }
}

// ---------------------------------------------------------------------------
extern "C" void kernel_launch(void* const* d_in, const int* in_sizes, int n_in,
                              void* d_out, int out_size, void* d_ws, size_t ws_size,
                              hipStream_t stream) {
    const float* x      = (const float*)d_in[0];
    const int*   ei     = (const int*)  d_in[1];
    const float* conv_w = (const float*)d_in[2];
    const float* conv_b = (const float*)d_in[3];
    const float* wl     = (const float*)d_in[4];
    const float* wr     = (const float*)d_in[5];
    const float* sb     = (const float*)d_in[6];
    const float* fc1w   = (const float*)d_in[7];
    const float* fc1b   = (const float*)d_in[8];
    const float* fc2w   = (const float*)d_in[9];
    const float* fc2b   = (const float*)d_in[10];
    const float* fc3w   = (const float*)d_in[11];
    const float* fc3b   = (const float*)d_in[12];
    float* out = (float*)d_out;

    ushort* hA   = (ushort*)d_ws;
    ushort* hB   = hA + SZH;
    ushort* agg  = hB + SZH;
    ushort* wc   = agg + SZH;
    ushort* aggP = wc + (size_t)2 * NPAD * KP;      // [256][KP]
    ushort* h2P  = aggP + (size_t)CCH * KP;         // [256][KP]
    ushort* poolt= h2P + (size_t)CCH * KP;          // [256][KP] tiny-GEMM out
    int*    off  = (int*)(poolt + (size_t)CCH * KP);
    int*    lst  = off + 128;

    build_csr_k<<<1, 256, 0, stream>>>(ei, off, lst);
    build_wc_k<<<(2 * NPAD * KP + 255) / 256, 256, 0, stream>>>(wl, wr, wc);
    {
        dim3 cgrid(NN, 4);
        conv1d_k<<<cgrid, 256, 0, stream>>>(x, conv_w, conv_b, hA);
    }

    dim3 tg(CCH, KP / 32);   // (256, 21)
    // L1: hA -> hB ; L2: hB -> hA
    seg_maxT_k<<<tg, 256, 0, stream>>>(hA, agg, off, lst);
    sage_gemm_k<<<MM / 128 * NT6, 256, 0, stream>>>(agg, hA, wc, sb, hB);
    seg_maxT_k<<<tg, 256, 0, stream>>>(hB, agg, off, lst);
    sage_gemm_k<<<MM / 128 * NT6, 256, 0, stream>>>(agg, hB, wc, sb, hA);
    // L3 pooled: aggP = mean_n(seg_max(hA)), h2P = mean_n(hA); tiny GEMM M=256
    seg_pool2_k<<<tg, 256, 0, stream>>>(hA, aggP, h2P, off, lst);
    sage_gemm_k<<<(CCH / 128) * NT6, 256, 0, stream>>>(aggP, h2P, wc, sb, poolt);
    head_k<<<CCH, 128, 0, stream>>>(poolt, fc1w, fc1b, fc2w, fc2b, fc3w, fc3b, out);
}

// Round 12
// 627.530 us; speedup vs baseline: 1.0570x; 1.0570x over previous
//
#include <hip/hip_runtime.h>
#include <hip/hip_bf16.h>
#include <math.h>

// Problem constants
#define NN 116           // nodes
#define NE 1160          // edges
#define CCH 256          // channels after conv
#define FF 653           // feature dim
#define KP 672           // padded feature stride (bf16), mult of 32
#define MM (NN*CCH)      // 29696 GEMM rows (= 232 * 128)
#define NPAD 768         // padded N for weight matrix (6 * 128)
#define NT6 (NPAD/128)   // 6 N-tiles
#define NKS (2*KP/32)    // 42 K-steps across the two concatenated passes
#define SZH ((size_t)MM*KP)   // elems per bf16 h buffer
#define FPAD 768         // padded f rows in conv im2col (6 * 128)
#define CK 128           // conv GEMM K: 16 in-ch x 8 padded taps

typedef unsigned short ushort;
typedef short bf16x8 __attribute__((ext_vector_type(8)));
typedef float f32x4 __attribute__((ext_vector_type(4)));

// ---- bf16 helpers (bit-level) ----------------------------------------------
__device__ __forceinline__ float bfbits_to_f(ushort u) {
    unsigned int w = ((unsigned int)u) << 16;
    return __uint_as_float(w);
}
__device__ __forceinline__ ushort f_to_bfbits(float f) {   // RTNE
    unsigned int u = __float_as_uint(f);
    u += 0x7FFFu + ((u >> 16) & 1u);
    return (ushort)(u >> 16);
}

__device__ __forceinline__ void gl_lds16(const void* g, void* l) {
    __builtin_amdgcn_global_load_lds(
        (const __attribute__((address_space(1))) unsigned int*)g,
        (__attribute__((address_space(3))) unsigned int*)l, 16, 0, 0);
}

// ---------------------------------------------------------------------------
// CSR build: per-dst incoming-edge source lists.
__global__ void build_csr_k(const int* __restrict__ ei, int* __restrict__ off,
                            int* __restrict__ lst) {
    __shared__ int s_cnt[NN];
    __shared__ int s_off[NN + 1];
    int t = threadIdx.x;
    for (int i = t; i < NN; i += blockDim.x) s_cnt[i] = 0;
    __syncthreads();
    for (int e = t; e < NE; e += blockDim.x) atomicAdd(&s_cnt[ei[NE + e]], 1);
    __syncthreads();
    if (t == 0) {
        s_off[0] = 0;
        for (int i = 0; i < NN; ++i) s_off[i + 1] = s_off[i] + s_cnt[i];
    }
    __syncthreads();
    for (int i = t; i < NN; i += blockDim.x) { off[i] = s_off[i]; s_cnt[i] = 0; }
    if (t == 0) off[NN] = s_off[NN];
    __syncthreads();
    for (int e = t; e < NE; e += blockDim.x) {
        int d = ei[NE + e];
        int p = atomicAdd(&s_cnt[d], 1);
        lst[s_off[d] + p] = ei[e];
    }
}

// ---------------------------------------------------------------------------
// Quantize + concat SAGE weights: Wc[2][NPAD][KP] bf16; pass0=Wl, pass1=Wr.
__global__ void build_wc_k(const float* __restrict__ wl, const float* __restrict__ wr,
                           ushort* __restrict__ wc) {
    int idx = blockIdx.x * 256 + threadIdx.x;
    const int total = 2 * NPAD * KP;
    if (idx >= total) return;
    int k = idx % KP;
    int rem = idx / KP;
    int n = rem % NPAD;
    int p = rem / NPAD;
    float v = 0.f;
    if (n < FF && k < FF) v = (p ? wr : wl)[(size_t)n * FF + k];
    wc[idx] = f_to_bfbits(v);
}

// ---------------------------------------------------------------------------
// Conv weights -> bf16 Wb[256 o][128 k], k = i*8+t, t<5 real taps else 0.
__global__ void wb_k(const float* __restrict__ w, ushort* __restrict__ wb) {
    int idx = blockIdx.x * 256 + threadIdx.x;     // o*128 + i*8 + t
    if (idx >= CCH * CK) return;
    int k = idx & 127, o = idx >> 7;
    int i = k >> 3, t = k & 7;
    float v = (t < 5) ? w[o * 80 + i * 5 + t] : 0.f;
    wb[idx] = f_to_bfbits(v);
}

// ---------------------------------------------------------------------------
// im2col: XB[(n,g)][f][i*8+t] = bf16(x[n][g*16+i][f+t]), f<653 (f+4<=656 in
// bounds). Rows f in [653,768) stay poisoned-but-finite — they only ever feed
// h's pad band, which is zero-weighted downstream (Wc k>=653 == 0).
__global__ __launch_bounds__(256) void im2col_k(const float* __restrict__ x,
                                                ushort* __restrict__ xb) {
    const int n = blockIdx.x, g = blockIdx.y;
    const float* xg = x + ((size_t)n * 64 + g * 16) * 657;
    ushort* slab = xb + ((size_t)(n * 4 + g)) * FPAD * CK;
    for (int u = threadIdx.x; u < FF * 16; u += 256) {
        int f = u >> 4, i = u & 15;          // i fast -> 16B stores contiguous
        const float* xp = xg + i * 657 + f;
        unsigned int e[5];
#pragma unroll
        for (int t = 0; t < 5; ++t) e[t] = f_to_bfbits(xp[t]);
        uint4 v;
        v.x = e[0] | (e[1] << 16);
        v.y = e[2] | (e[3] << 16);
        v.z = e[4];                            // taps 5..7 zero
        v.w = 0u;
        *(uint4*)(slab + (size_t)f * CK + i * 8) = v;
    }
}

// ---------------------------------------------------------------------------
// Conv as MFMA GEMM: h[n][o][f] = bias[o] + sum_k Wb[o][k] * XB[n,g][f][k].
// Tile 64(o) x 128(f), 4 waves (each: all 64 o x 32 f), K=128 = 4 steps.
// Same both-sides swizzle + 2-phase dbuf as sage_gemm (proven R5-R11).
__global__ __launch_bounds__(256) void convgemm_k(
    const ushort* __restrict__ xb, const ushort* __restrict__ wb,
    const float* __restrict__ bias, ushort* __restrict__ h) {
    __shared__ ushort As[2][64 * 32];
    __shared__ ushort Bs[2][128 * 32];
    const int bid   = blockIdx.x;
    const int ftile = bid % 6;
    const int rem   = bid / 6;
    const int g     = rem & 3;
    const int n     = rem >> 2;
    const int tid = threadIdx.x, lane = tid & 63, wv = tid >> 6;
    const int srow = lane >> 2, schunk = lane & 3;
    const int schk = (schunk ^ ((srow >> 1) & 3)) * 8;
    const int lr = lane & 15, cc = lane >> 4;
    const int kc = (cc ^ ((lr >> 1) & 3)) * 8;
    const int lg = lane >> 4;
    const ushort* slab  = xb + ((size_t)(n * 4 + g)) * FPAD * CK;
    const ushort* wbase = wb + (size_t)g * 64 * CK;

    f32x4 acc[4][2];
#pragma unroll
    for (int i = 0; i < 4; ++i)
#pragma unroll
        for (int j = 0; j < 2; ++j) acc[i][j] = 0.f;

#define CSTAGE(b, ks) do {                                                    \
        int _k0 = (ks) * 32;                                                  \
        const ushort* _ga = wbase + (size_t)(wv * 16 + srow) * CK + _k0 + schk; \
        const ushort* _gb = slab + (size_t)(ftile * 128 + wv * 16 + srow) * CK + _k0 + schk; \
        gl_lds16(_ga, &As[b][wv * 16 * 32]);                                  \
        gl_lds16(_gb, &Bs[b][wv * 16 * 32]);                                  \
        gl_lds16(_gb + (size_t)64 * CK, &Bs[b][wv * 16 * 32 + 64 * 32]);      \
    } while (0)

#define CCOMP(b) do {                                                         \
        bf16x8 _af[4], _bf[2];                                                \
        _Pragma("unroll")                                                     \
        for (int i = 0; i < 4; ++i)                                           \
            _af[i] = *(const bf16x8*)&As[b][(i * 16 + lr) * 32 + kc];         \
        _Pragma("unroll")                                                     \
        for (int j = 0; j < 2; ++j)                                           \
            _bf[j] = *(const bf16x8*)&Bs[b][(wv * 32 + j * 16 + lr) * 32 + kc]; \
        _Pragma("unroll")                                                     \
        for (int i = 0; i < 4; ++i)                                           \
            _Pragma("unroll")                                                 \
            for (int j = 0; j < 2; ++j)                                       \
                acc[i][j] = __builtin_amdgcn_mfma_f32_16x16x32_bf16(          \
                    _af[i], _bf[j], acc[i][j], 0, 0, 0);                      \
    } while (0)

    CSTAGE(0, 0); __syncthreads();
    CSTAGE(1, 1); CCOMP(0); __syncthreads();   // ks0
    CSTAGE(0, 2); CCOMP(1); __syncthreads();   // ks1
    CSTAGE(1, 3); CCOMP(0); __syncthreads();   // ks2
    CCOMP(1);                                  // ks3
#undef CSTAGE
#undef CCOMP

#pragma unroll
    for (int i = 0; i < 4; ++i) {
#pragma unroll
        for (int j = 0; j < 2; ++j) {
            int fl = ftile * 128 + wv * 32 + j * 16 + lr;
            if (fl >= KP) continue;
#pragma unroll
            for (int r = 0; r < 4; ++r) {
                int oa = g * 64 + i * 16 + lg * 4 + r;
                float v = acc[i][j][r] + bias[oa];
                h[(size_t)(n * CCH + oa) * KP + fl] = f_to_bfbits(v);
            }
        }
    }
}

// ---------------------------------------------------------------------------
// Transposed segment-max (layers 1,2). Block = (channel c, 32-feature chunk).
__global__ __launch_bounds__(256) void seg_maxT_k(
    const ushort* __restrict__ h, ushort* __restrict__ agg,
    const int* __restrict__ off, const int* __restrict__ lst) {
    __shared__ uint4 sh[NN * 4];            // [n][sub] : 32 bf16 per node
    const int c  = blockIdx.x;              // 0..255
    const int f0 = blockIdx.y * 32;         // 0..640
    const int t  = threadIdx.x;
    for (int u = t; u < NN * 4; u += 256) {
        int n = u >> 2, sub = u & 3;
        sh[u] = *(const uint4*)(h + ((size_t)(n * CCH + c)) * KP + f0 + sub * 8);
    }
    __syncthreads();
    for (int u = t; u < NN * 4; u += 256) {
        int n = u >> 2, sub = u & 3;
        int o0 = off[n], o1 = off[n + 1];
        uint4 outv;
        if (o0 == o1) {
            outv = make_uint4(0, 0, 0, 0);
        } else {
            float m[8];
#pragma unroll
            for (int i = 0; i < 8; ++i) m[i] = -3.4e38f;
            for (int e = o0; e < o1; ++e) {
                int s = lst[e];
                uint4 v = sh[s * 4 + sub];
                unsigned int uu[4] = {v.x, v.y, v.z, v.w};
#pragma unroll
                for (int q = 0; q < 4; ++q) {
                    float lo = __uint_as_float(uu[q] << 16);
                    float hi = __uint_as_float(uu[q] & 0xFFFF0000u);
                    m[2*q]   = fmaxf(m[2*q],   lo);
                    m[2*q+1] = fmaxf(m[2*q+1], hi);
                }
            }
            unsigned int o[4];
#pragma unroll
            for (int q = 0; q < 4; ++q) {
                unsigned int a  = __float_as_uint(m[2*q])   >> 16;
                unsigned int bq = __float_as_uint(m[2*q+1]) & 0xFFFF0000u;
                o[q] = a | bq;
            }
            outv = make_uint4(o[0], o[1], o[2], o[3]);
        }
        *(uint4*)(agg + ((size_t)(n * CCH + c)) * KP + f0 + sub * 8) = outv;
    }
}

// ---------------------------------------------------------------------------
// Layer-3 fused: aggP[c][f] = mean_n seg_max(h)[n,c,f], h2P[c][f] = mean_n h.
__global__ __launch_bounds__(256) void seg_pool2_k(
    const ushort* __restrict__ h, ushort* __restrict__ aggP,
    ushort* __restrict__ h2P,
    const int* __restrict__ off, const int* __restrict__ lst) {
    __shared__ uint4 sh[NN * 4];
    __shared__ float pm[NN][32];            // per-node maxes fp32
    const int c  = blockIdx.x;
    const int f0 = blockIdx.y * 32;
    const int t  = threadIdx.x;
    for (int u = t; u < NN * 4; u += 256) {
        int n = u >> 2, sub = u & 3;
        sh[u] = *(const uint4*)(h + ((size_t)(n * CCH + c)) * KP + f0 + sub * 8);
    }
    __syncthreads();
    for (int u = t; u < NN * 4; u += 256) {
        int n = u >> 2, sub = u & 3;
        int o0 = off[n], o1 = off[n + 1];
        float m[8];
        if (o0 == o1) {
#pragma unroll
            for (int i = 0; i < 8; ++i) m[i] = 0.f;
        } else {
#pragma unroll
            for (int i = 0; i < 8; ++i) m[i] = -3.4e38f;
            for (int e = o0; e < o1; ++e) {
                int s = lst[e];
                uint4 v = sh[s * 4 + sub];
                unsigned int uu[4] = {v.x, v.y, v.z, v.w};
#pragma unroll
                for (int q = 0; q < 4; ++q) {
                    float lo = __uint_as_float(uu[q] << 16);
                    float hi = __uint_as_float(uu[q] & 0xFFFF0000u);
                    m[2*q]   = fmaxf(m[2*q],   lo);
                    m[2*q+1] = fmaxf(m[2*q+1], hi);
                }
            }
#pragma unroll
            for (int i = 0; i < 8; ++i)
                m[i] = __uint_as_float(__float_as_uint(m[i]) & 0xFFFF0000u);
        }
#pragma unroll
        for (int i = 0; i < 8; ++i) pm[n][sub * 8 + i] = m[i];
    }
    __syncthreads();
    if (t < 32) {
        const float inv = 1.0f / NN;
        float sa = 0.f, s2 = 0.f;
        for (int n = 0; n < NN; ++n) {
            sa += pm[n][t];
            uint4 v = sh[n * 4 + (t >> 3)];
            unsigned int w = ((const unsigned int*)&v)[(t >> 1) & 3];
            float hv = (t & 1) ? __uint_as_float(w & 0xFFFF0000u)
                               : __uint_as_float(w << 16);
            s2 += hv;
        }
        aggP[(size_t)c * KP + f0 + t] = f_to_bfbits(sa * inv);
        h2P [(size_t)c * KP + f0 + t] = f_to_bfbits(s2 * inv);
    }
}

// ---------------------------------------------------------------------------
// MFMA SAGE GEMM, 2-phase prefetch (R9-verified 128² ceiling).
__global__ __launch_bounds__(256) void sage_gemm_k(
    const ushort* __restrict__ Agg, const ushort* __restrict__ Hcur,
    const ushort* __restrict__ Wc, const float* __restrict__ bias,
    ushort* __restrict__ Hnxt)
{
    __shared__ ushort As[2][128 * 32];
    __shared__ ushort Bs[2][128 * 32];
    const int bid = blockIdx.x;
    const int nwg = gridDim.x;
    const int q   = nwg >> 3, r = nwg & 7;
    const int xcd = bid & 7,  jj = bid >> 3;
    const int wgid = (xcd < r ? xcd * (q + 1) : r * (q + 1) + (xcd - r) * q) + jj;
    const int mt = wgid / NT6;
    const int nt = wgid - mt * NT6;
    const int bm = mt * 128;
    const int bn = nt * 128;
    const int tid  = threadIdx.x;
    const int lane = tid & 63;
    const int wid  = tid >> 6;
    const int wm = (wid >> 1) * 64;
    const int wn = (wid & 1) * 64;

    f32x4 acc[4][4];
#pragma unroll
    for (int i = 0; i < 4; ++i)
#pragma unroll
        for (int j = 0; j < 4; ++j) acc[i][j] = 0.f;

    const int srow   = lane >> 2;
    const int schunk = lane & 3;
    const int schk   = (schunk ^ ((srow >> 1) & 3)) * 8;
    const int lr  = lane & 15;
    const int cc  = lane >> 4;
    const int kc  = (cc ^ ((lr >> 1) & 3)) * 8;
    const int ldsoff = wid * 16 * 32;

#define STAGE(b, kk) do {                                                     \
        int _kk = (kk);                                                       \
        const ushort* _Ab = (_kk < 21) ? Agg : Hcur;                          \
        const ushort* _Wb = Wc + (size_t)(_kk < 21 ? 0 : 1) * NPAD * KP;      \
        int _k0 = (_kk < 21 ? _kk : _kk - 21) * 32;                           \
        const ushort* _ga = _Ab + (size_t)(bm + wid * 16 + srow) * KP + _k0 + schk; \
        const ushort* _gb = _Wb + (size_t)(bn + wid * 16 + srow) * KP + _k0 + schk; \
        gl_lds16(_ga, &As[b][ldsoff]);                                        \
        gl_lds16(_ga + (size_t)64 * KP, &As[b][ldsoff + 64 * 32]);            \
        gl_lds16(_gb, &Bs[b][ldsoff]);                                        \
        gl_lds16(_gb + (size_t)64 * KP, &Bs[b][ldsoff + 64 * 32]);            \
    } while (0)

#define COMPUTE(b) do {                                                       \
        bf16x8 _af[4], _bf[4];                                                \
        _Pragma("unroll")                                                     \
        for (int i = 0; i < 4; ++i)                                           \
            _af[i] = *(const bf16x8*)&As[b][(wm + i * 16 + lr) * 32 + kc];    \
        _Pragma("unroll")                                                     \
        for (int j = 0; j < 4; ++j)                                           \
            _bf[j] = *(const bf16x8*)&Bs[b][(wn + j * 16 + lr) * 32 + kc];    \
        _Pragma("unroll")                                                     \
        for (int i = 0; i < 4; ++i)                                           \
            _Pragma("unroll")                                                 \
            for (int j = 0; j < 4; ++j)                                       \
                acc[i][j] = __builtin_amdgcn_mfma_f32_16x16x32_bf16(          \
                    _af[i], _bf[j], acc[i][j], 0, 0, 0);                      \
    } while (0)

    STAGE(0, 0);
    __syncthreads();
#pragma unroll 1
    for (int kk = 0; kk < NKS; kk += 2) {
        STAGE(1, kk + 1);
        COMPUTE(0);
        __syncthreads();
        if (kk + 2 < NKS) STAGE(0, kk + 2);
        COMPUTE(1);
        __syncthreads();
    }
#undef STAGE
#undef COMPUTE

    const int lg = lane >> 4;
#pragma unroll
    for (int j = 0; j < 4; ++j) {
        int n = bn + wn + j * 16 + lr;
        if (n >= KP) continue;
        bool valid = n < FF;
        float bv = valid ? bias[n] : 0.f;
#pragma unroll
        for (int i = 0; i < 4; ++i) {
#pragma unroll
            for (int rgi = 0; rgi < 4; ++rgi) {
                int m = bm + wm + i * 16 + lg * 4 + rgi;
                float v = valid ? (acc[i][j][rgi] + bv) : 0.f;
                Hnxt[(size_t)m * KP + n] = f_to_bfbits(v);
            }
        }
    }
}

// ---------------------------------------------------------------------------
__device__ __forceinline__ float gelu_exact(float v) {
    return 0.5f * v * (1.0f + erff(v * 0.70710678118654752f));
}

__global__ void head_k(const ushort* __restrict__ pool,
                       const float* __restrict__ w1, const float* __restrict__ b1,
                       const float* __restrict__ w2, const float* __restrict__ b2,
                       const float* __restrict__ w3, const float* __restrict__ b3,
                       float* __restrict__ out) {
    __shared__ float row[FF];
    __shared__ float h1[128];
    __shared__ float h2[32];
    __shared__ float sc[4];
    const int c = blockIdx.x;
    const int t = threadIdx.x;
    for (int i = t; i < FF; i += 128) row[i] = bfbits_to_f(pool[(size_t)c * KP + i]);
    __syncthreads();
    {
        const float* wp = w1 + (size_t)t * FF;
        float s = b1[t];
        for (int i = 0; i < FF; ++i) s = fmaf(row[i], wp[i], s);
        h1[t] = gelu_exact(s);
    }
    __syncthreads();
    if (t < 32) {
        const float* wp = w2 + (size_t)t * 128;
        float s = b2[t];
#pragma unroll
        for (int i = 0; i < 128; ++i) s = fmaf(h1[i], wp[i], s);
        h2[t] = gelu_exact(s);
    }
    __syncthreads();
    if (t < 4) {
        const float* wp = w3 + (size_t)t * 32;
        float s = b3[t];
#pragma unroll
        for (int i = 0; i < 32; ++i) s = fmaf(h2[i], wp[i], s);
        sc[t] = s;
    }
    __syncthreads();
    if (t < 4) {
        float mx = fmaxf(fmaxf(sc[0], sc[1]), fmaxf(sc[2], sc[3]));
        float e0 = __expf(sc[0] - mx), e1 = __expf(sc[1] - mx);
        float e2 = __expf(sc[2] - mx), e3 = __expf(sc[3] - mx);
        float inv = 1.0f / (e0 + e1 + e2 + e3);
        float ev = (t == 0) ? e0 : (t == 1) ? e1 : (t == 2) ? e2 : e3;
        out[(size_t)c * 4 + t] = ev * inv;
    }
}

// ---------------------------------------------------------------------------
extern "C" void kernel_launch(void* const* d_in, const int* in_sizes, int n_in,
                              void* d_out, int out_size, void* d_ws, size_t ws_size,
                              hipStream_t stream) {
    const float* x      = (const float*)d_in[0];
    const int*   ei     = (const int*)  d_in[1];
    const float* conv_w = (const float*)d_in[2];
    const float* conv_b = (const float*)d_in[3];
    const float* wl     = (const float*)d_in[4];
    const float* wr     = (const float*)d_in[5];
    const float* sb     = (const float*)d_in[6];
    const float* fc1w   = (const float*)d_in[7];
    const float* fc1b   = (const float*)d_in[8];
    const float* fc2w   = (const float*)d_in[9];
    const float* fc2b   = (const float*)d_in[10];
    const float* fc3w   = (const float*)d_in[11];
    const float* fc3b   = (const float*)d_in[12];
    float* out = (float*)d_out;

    ushort* hA   = (ushort*)d_ws;
    ushort* hB   = hA + SZH;
    ushort* agg  = hB + SZH;
    ushort* wc   = agg + SZH;
    ushort* aggP = wc + (size_t)2 * NPAD * KP;      // [256][KP]
    ushort* h2P  = aggP + (size_t)CCH * KP;         // [256][KP]
    ushort* poolt= h2P + (size_t)CCH * KP;          // [256][KP] tiny-GEMM out
    ushort* wb   = poolt + (size_t)CCH * KP;        // [256][128] conv weights
    ushort* xb   = wb + (size_t)CCH * CK;           // [464][768][128] im2col
    int*    off  = (int*)(xb + (size_t)NN * 4 * FPAD * CK);
    int*    lst  = off + 128;

    build_csr_k<<<1, 256, 0, stream>>>(ei, off, lst);
    build_wc_k<<<(2 * NPAD * KP + 255) / 256, 256, 0, stream>>>(wl, wr, wc);
    wb_k<<<(CCH * CK + 255) / 256, 256, 0, stream>>>(conv_w, wb);
    im2col_k<<<dim3(NN, 4), 256, 0, stream>>>(x, xb);
    convgemm_k<<<NN * 4 * 6, 256, 0, stream>>>(xb, wb, conv_b, hA);

    dim3 tg(CCH, KP / 32);   // (256, 21)
    // L1: hA -> hB ; L2: hB -> hA
    seg_maxT_k<<<tg, 256, 0, stream>>>(hA, agg, off, lst);
    sage_gemm_k<<<MM / 128 * NT6, 256, 0, stream>>>(agg, hA, wc, sb, hB);
    seg_maxT_k<<<tg, 256, 0, stream>>>(hB, agg, off, lst);
    sage_gemm_k<<<MM / 128 * NT6, 256, 0, stream>>>(agg, hB, wc, sb, hA);
    // L3 pooled: aggP = mean_n(seg_max(hA)), h2P = mean_n(hA); tiny GEMM M=256
    seg_pool2_k<<<tg, 256, 0, stream>>>(hA, aggP, h2P, off, lst);
    sage_gemm_k<<<(CCH / 128) * NT6, 256, 0, stream>>>(aggP, h2P, wc, sb, poolt);
    head_k<<<CCH, 128, 0, stream>>>(poolt, fc1w, fc1b, fc2w, fc2b, fc3w, fc3b, out);
}